// Round 1
// 851.584 us; speedup vs baseline: 1.2773x; 1.2773x over previous
//
#include <hip/hip_runtime.h>
#include <hip/hip_bf16.h>

typedef __bf16 bf16_t;
typedef bf16_t bf16x8 __attribute__((ext_vector_type(8)));
typedef bf16_t bf16x4v __attribute__((ext_vector_type(4)));
typedef float f32x4 __attribute__((ext_vector_type(4)));

// async 16B global->LDS (direct, no VGPR round trip)
__device__ __forceinline__ void gll16(const bf16_t* g, bf16_t* l) {
    __builtin_amdgcn_global_load_lds(
        (const __attribute__((address_space(1))) unsigned int*)g,
        (__attribute__((address_space(3))) unsigned int*)l, 16, 0, 0);
}

// ---------------------------------------------------------------------------
// fp32 -> bf16 elementwise (n multiple of 4)
// ---------------------------------------------------------------------------
__global__ __launch_bounds__(256)
void cvt_f32_bf16(const float* __restrict__ in, bf16_t* __restrict__ out, int n4)
{
    int i = blockIdx.x * 256 + threadIdx.x;
    if (i < n4) {
        float4 v = ((const float4*)in)[i];
        bf16x4v o = { (bf16_t)v.x, (bf16_t)v.y, (bf16_t)v.z, (bf16_t)v.w };
        *(bf16x4v*)&out[i * 4] = o;
    }
}

// ---------------------------------------------------------------------------
// Reorder conv weights (O,C,7) fp32 -> bf16 planes [(i*7+kk)][o][c]
// ---------------------------------------------------------------------------
__global__ __launch_bounds__(256)
void reorder_convw(const float* w0, const float* w1, const float* w2,
                   const float* w3, const float* w4, bf16_t* __restrict__ out)
{
    int gid = blockIdx.x * 256 + threadIdx.x;       // < 5*1024*1024
    int i = gid >> 20, rem = gid & 1048575;
    int o = rem >> 10, c = rem & 1023;
    const float* ws[5] = {w0, w1, w2, w3, w4};
    const float* src = ws[i] + (size_t)o * 7168 + c * 7;
    #pragma unroll
    for (int kk = 0; kk < 7; kk++)
        out[((size_t)(i * 7 + kk) << 20) + (o << 10) + c] = (bf16_t)src[kk];
}

__global__ __launch_bounds__(256)
void gather_bias(const float* b0, const float* b1, const float* b2,
                 const float* b3, const float* b4, float* __restrict__ out,
                 bf16_t* __restrict__ zp)
{
    int idx = blockIdx.x * 256 + threadIdx.x;       // < 5120
    if (blockIdx.x == 0 && threadIdx.x < 32) zp[threadIdx.x] = (bf16_t)0.0f;
    const float* bs[5] = {b0, b1, b2, b3, b4};
    out[idx] = bs[idx >> 10][idx & 1023];
}

// ---------------------------------------------------------------------------
// bf16 MFMA NT GEMM: out[n, m] = sum_k A[n,k]*B[m,k] + bias[...]
// Tile 128x128, BK=32, 4 waves (2x2 of 64x64), 16x16x32 MFMA.
// BIAS_ROW: bias indexed by n (row) instead of oc0+m (used for transposed-out
// GEMMs where the "output feature" axis is n).
// ---------------------------------------------------------------------------
template<bool CONV, bool OUT_BF16, bool BIAS_ROW = false>
__global__ __launch_bounds__(256)
void mfma_gemm(const bf16_t* __restrict__ A, const bf16_t* __restrict__ Bw,
               const float* __restrict__ bias, void* __restrict__ outv,
               const bf16_t* __restrict__ zp,
               int Kd, int lda, int ldb, int ldo, int out_col0)
{
    __shared__ __align__(16) bf16_t As[128 * 32];
    __shared__ __align__(16) bf16_t Bs[128 * 32];
    const int t = threadIdx.x;
    const int lane = t & 63, wave = t >> 6;
    const int wn = (wave & 1) * 64, wm = (wave >> 1) * 64;
    const int q = lane >> 4, lr = lane & 15;
    const int mt = CONV ? (blockIdx.x & 7) : blockIdx.x;
    const int conv_i = CONV ? (blockIdx.x >> 3) : 0;
    const int m0 = mt * 128, n0 = blockIdx.y * 128;
    const int srow = lane >> 2, sseg = lane & 3;   // staging row/16B-seg

    f32x4 acc[4][4];
    #pragma unroll
    for (int a = 0; a < 4; a++)
        #pragma unroll
        for (int b = 0; b < 4; b++) acc[a][b] = (f32x4){0.f, 0.f, 0.f, 0.f};

    const int taps = CONV ? 7 : 1;
    for (int kk = 0; kk < taps; kk++) {
        const bf16_t* Bp = CONV ? (Bw + ((size_t)(conv_i * 7 + kk) << 20)) : Bw;
        const int shift = CONV ? ((kk - 3) << conv_i) : 0;
        for (int k0 = 0; k0 < Kd; k0 += 32) {
            #pragma unroll
            for (int p = 0; p < 2; p++) {
                const int slab = p * 64 + wave * 16;     // 16-row slab base
                const int rr = slab + srow;
                // A (with conv temporal shift, zero page when OOB)
                const bf16_t* ga;
                if (CONV) {
                    int n = n0 + rr;
                    int tg = (n & 255) + shift;
                    ga = ((unsigned)tg < 256u)
                       ? A + (size_t)((n & ~255) + tg) * lda + k0 + sseg * 8
                       : zp + sseg * 8;
                } else {
                    ga = A + (size_t)(n0 + rr) * lda + k0 + sseg * 8;
                }
                gll16(ga, &As[slab * 32]);
                // B
                gll16(Bp + (size_t)(m0 + rr) * ldb + k0 + sseg * 8, &Bs[slab * 32]);
            }
            __syncthreads();    // drains vmcnt -> LDS valid
            bf16x8 af[4], bfv[4];
            #pragma unroll
            for (int f = 0; f < 4; f++) {
                af[f]  = *(bf16x8*)&As[(wn + f * 16 + lr) * 32 + q * 8];
                bfv[f] = *(bf16x8*)&Bs[(wm + f * 16 + lr) * 32 + q * 8];
            }
            #pragma unroll
            for (int fn = 0; fn < 4; fn++)
                #pragma unroll
                for (int fm = 0; fm < 4; fm++)
                    acc[fn][fm] = __builtin_amdgcn_mfma_f32_16x16x32_bf16(
                        af[fn], bfv[fm], acc[fn][fm], 0, 0, 0);
            __syncthreads();
        }
    }

    const int oc0 = CONV ? (conv_i << 10) : out_col0;
    #pragma unroll
    for (int fn = 0; fn < 4; fn++) {
        #pragma unroll
        for (int r = 0; r < 4; r++) {
            int n = n0 + wn + fn * 16 + q * 4 + r;
            #pragma unroll
            for (int fm = 0; fm < 4; fm++) {
                int m = m0 + wm + fm * 16 + lr;
                float v = acc[fn][fm][r];
                if (bias) v += bias[BIAS_ROW ? n : (oc0 + m)];
                if (OUT_BF16)
                    ((bf16_t*)outv)[(size_t)n * ldo + oc0 + m] = (bf16_t)v;
                else
                    ((float*)outv)[(size_t)n * ldo + oc0 + m] = v;
            }
        }
    }
}

// ---------------------------------------------------------------------------
// LayerNorm (eps 1e-5) + exact GELU, in place on z (fp32) + bf16 copy zb.
// ---------------------------------------------------------------------------
__global__ __launch_bounds__(256)
void ln_gelu(float* __restrict__ z, bf16_t* __restrict__ zb,
             const float* __restrict__ g, const float* __restrict__ b)
{
    __shared__ float r1[256], r2[256];
    const int n = blockIdx.x, t = threadIdx.x;
    float* row = z + (size_t)n * 1024;
    float x[4], s = 0.f, s2 = 0.f;
    #pragma unroll
    for (int u = 0; u < 4; u++) {
        x[u] = row[t + u * 256];
        s += x[u]; s2 += x[u] * x[u];
    }
    r1[t] = s; r2[t] = s2;
    __syncthreads();
    for (int off = 128; off > 0; off >>= 1) {
        if (t < off) { r1[t] += r1[t + off]; r2[t] += r2[t + off]; }
        __syncthreads();
    }
    const float mu  = r1[0] * (1.0f / 1024.0f);
    const float var = r2[0] * (1.0f / 1024.0f) - mu * mu;
    const float rstd = rsqrtf(var + 1e-5f);
    #pragma unroll
    for (int u = 0; u < 4; u++) {
        int c = t + u * 256;
        float y = (x[u] - mu) * rstd * g[c] + b[c];
        float gv = 0.5f * y * (1.0f + erff(y * 0.70710678118654752f));
        row[c] = gv;
        zb[(size_t)n * 1024 + c] = (bf16_t)gv;
    }
}

// ---------------------------------------------------------------------------
// MFMA flash attention.
// Grid (2 i-tiles x 16 heads x 8 batch) = 256 blocks, 4 waves.
// Each wave owns 32 query rows; K/V iterated in 64-token chunks with online
// softmax (fp32 m/l, bf16 P via wave-private LDS relayout).
// q,k: [2048][1024] bf16 row-major.  vt: [1024 dims][2048 tokens] bf16
// (produced by the operand-swapped V projection GEMM).  ctx: [2048][1024].
// All LDS tiles XOR-swizzled: 16B slot ^= (row&7)  (row stride 128B would
// otherwise be a 32-way bank conflict on ds_read_b128).
// ---------------------------------------------------------------------------
__global__ __launch_bounds__(256)
void attn_mfma(const bf16_t* __restrict__ qg, const bf16_t* __restrict__ kg,
               const bf16_t* __restrict__ vt, bf16_t* __restrict__ ctx)
{
    const int it = blockIdx.x, h = blockIdx.y, bb = blockIdx.z;
    const int t = threadIdx.x, lane = t & 63, wave = t >> 6;
    const int q4 = lane >> 4, lr = lane & 15;
    const size_t tokbase = (size_t)bb * 262144 + (size_t)h * 64;

    __shared__ __align__(16) bf16_t Qs[4][32 * 64];   // per-wave Q rows
    __shared__ __align__(16) bf16_t Ks[64 * 64];      // K chunk  [j][d]
    __shared__ __align__(16) bf16_t Vs[64 * 64];      // Vt chunk [d][j]
    __shared__ __align__(16) bf16_t Ps[4][32 * 64];   // per-wave P tile [i][j]

    // ---- stage Q (128 rows x 64, swizzled), cooperative ----
    {
        const int itbase = it * 128;
        #pragma unroll
        for (int rep = 0; rep < 4; rep++) {
            int idx = rep * 256 + t;
            int rl = idx >> 3, seg = idx & 7;
            bf16x8 v = *(const bf16x8*)&qg[tokbase + (size_t)(itbase + rl) * 1024 + seg * 8];
            *(bf16x8*)&Qs[rl >> 5][(rl & 31) * 64 + ((seg ^ (rl & 7)) << 3)] = v;
        }
    }

    f32x4 o[2][4];                 // O accum: [fn rows][fd d-frag]
    float mrow[2][4], lrow[2][4];  // online softmax state per (fn, r)
    #pragma unroll
    for (int fn = 0; fn < 2; fn++)
        #pragma unroll
        for (int x = 0; x < 4; x++) {
            o[fn][x] = (f32x4){0.f, 0.f, 0.f, 0.f};
            mrow[fn][x] = -1e30f; lrow[fn][x] = 0.f;
        }

    for (int j0 = 0; j0 < 256; j0 += 64) {
        __syncthreads();           // prev chunk's K/V reads done (also covers Q stage)
        // ---- stage K chunk [64 j][64 d] and Vt chunk [64 d][64 j], swizzled ----
        #pragma unroll
        for (int rep = 0; rep < 2; rep++) {
            int idx = rep * 256 + t;
            int rl = idx >> 3, seg = idx & 7;
            bf16x8 kv = *(const bf16x8*)&kg[tokbase + (size_t)(j0 + rl) * 1024 + seg * 8];
            *(bf16x8*)&Ks[rl * 64 + ((seg ^ (rl & 7)) << 3)] = kv;
            bf16x8 vv = *(const bf16x8*)&vt[(size_t)(h * 64 + rl) * 2048 + bb * 256 + j0 + seg * 8];
            *(bf16x8*)&Vs[rl * 64 + ((seg ^ (rl & 7)) << 3)] = vv;
        }
        __syncthreads();

        // ---- S = Q K^T  (wave's 32 rows x 64 j) ----
        f32x4 s[2][4];
        #pragma unroll
        for (int fn = 0; fn < 2; fn++)
            #pragma unroll
            for (int fm = 0; fm < 4; fm++) s[fn][fm] = (f32x4){0.f, 0.f, 0.f, 0.f};
        #pragma unroll
        for (int kk = 0; kk < 2; kk++) {
            bf16x8 aq[2], bk[4];
            #pragma unroll
            for (int fn = 0; fn < 2; fn++) {
                int row = fn * 16 + lr;
                aq[fn] = *(bf16x8*)&Qs[wave][row * 64 + (((kk * 4 + q4) ^ (row & 7)) << 3)];
            }
            #pragma unroll
            for (int fm = 0; fm < 4; fm++) {
                int row = fm * 16 + lr;
                bk[fm] = *(bf16x8*)&Ks[row * 64 + (((kk * 4 + q4) ^ (row & 7)) << 3)];
            }
            #pragma unroll
            for (int fn = 0; fn < 2; fn++)
                #pragma unroll
                for (int fm = 0; fm < 4; fm++)
                    s[fn][fm] = __builtin_amdgcn_mfma_f32_16x16x32_bf16(
                        aq[fn], bk[fm], s[fn][fm], 0, 0, 0);
        }

        // ---- online softmax update + P (bf16) into wave-private LDS ----
        #pragma unroll
        for (int fn = 0; fn < 2; fn++) {
            #pragma unroll
            for (int r = 0; r < 4; r++) {
                float sv[4];
                #pragma unroll
                for (int fm = 0; fm < 4; fm++) sv[fm] = s[fn][fm][r] * 0.125f;
                float rm = fmaxf(fmaxf(sv[0], sv[1]), fmaxf(sv[2], sv[3]));
                rm = fmaxf(rm, __shfl_xor(rm, 1));
                rm = fmaxf(rm, __shfl_xor(rm, 2));
                rm = fmaxf(rm, __shfl_xor(rm, 4));
                rm = fmaxf(rm, __shfl_xor(rm, 8));
                float mold = mrow[fn][r];
                float mnew = fmaxf(mold, rm);
                float scl = __expf(mold - mnew);
                mrow[fn][r] = mnew;
                int prow = fn * 16 + q4 * 4 + r;
                float psum = 0.f;
                #pragma unroll
                for (int fm = 0; fm < 4; fm++) {
                    float p = __expf(sv[fm] - mnew);
                    psum += p;
                    int col = fm * 16 + lr;
                    Ps[wave][prow * 64 + (col ^ ((prow & 7) << 3))] = (bf16_t)p;
                }
                psum += __shfl_xor(psum, 1);
                psum += __shfl_xor(psum, 2);
                psum += __shfl_xor(psum, 4);
                psum += __shfl_xor(psum, 8);
                lrow[fn][r] = lrow[fn][r] * scl + psum;
                #pragma unroll
                for (int fd = 0; fd < 4; fd++) o[fn][fd][r] *= scl;
            }
        }

        // ---- O += P V  (wave-private Ps: in-order same-wave DS, no barrier) ----
        #pragma unroll
        for (int kk = 0; kk < 2; kk++) {
            bf16x8 ap[2], bvf[4];
            #pragma unroll
            for (int fn = 0; fn < 2; fn++) {
                int row = fn * 16 + lr;
                ap[fn] = *(bf16x8*)&Ps[wave][row * 64 + (((kk * 4 + q4) ^ (row & 7)) << 3)];
            }
            #pragma unroll
            for (int fd = 0; fd < 4; fd++) {
                int row = fd * 16 + lr;
                bvf[fd] = *(bf16x8*)&Vs[row * 64 + (((kk * 4 + q4) ^ (row & 7)) << 3)];
            }
            #pragma unroll
            for (int fn = 0; fn < 2; fn++)
                #pragma unroll
                for (int fd = 0; fd < 4; fd++)
                    o[fn][fd] = __builtin_amdgcn_mfma_f32_16x16x32_bf16(
                        ap[fn], bvf[fd], o[fn][fd], 0, 0, 0);
        }
    }

    // ---- epilogue: normalize, write ctx ----
    const int i0 = it * 128 + wave * 32;
    #pragma unroll
    for (int fn = 0; fn < 2; fn++) {
        #pragma unroll
        for (int r = 0; r < 4; r++) {
            float inv = 1.0f / lrow[fn][r];
            int row = i0 + fn * 16 + q4 * 4 + r;
            #pragma unroll
            for (int fd = 0; fd < 4; fd++) {
                int col = h * 64 + fd * 16 + lr;
                ctx[(size_t)bb * 262144 + (size_t)row * 1024 + col] =
                    (bf16_t)(o[fn][fd][r] * inv);
            }
        }
    }
}

// ---------------------------------------------------------------------------
// GAT logits, TRANSPOSED out: e1t[h][n] = hg[n,h,:].a1 ; e2t likewise.
// ---------------------------------------------------------------------------
__global__ __launch_bounds__(256)
void gat_e(const float* __restrict__ hg, const float* __restrict__ a1,
           const float* __restrict__ a2, float* __restrict__ e1t,
           float* __restrict__ e2t)
{
    int id = blockIdx.x * 256 + threadIdx.x;  // < 16384
    int h = id >> 11, n = id & 2047;
    const float* hr = hg + (size_t)n * 1024 + h * 128;
    float s1 = 0.f, s2 = 0.f;
    for (int d = 0; d < 128; d++) {
        float x = hr[d];
        s1 += x * a1[d];
        s2 += x * a2[d];
    }
    e1t[id] = s1; e2t[id] = s2;
}

// ---------------------------------------------------------------------------
// Transpose hg (2048 x 1024, fp32) -> hgT (1024 x 2048, bf16), 32x32 tiles.
// ---------------------------------------------------------------------------
__global__ __launch_bounds__(256)
void transpose_hg(const float* __restrict__ in, bf16_t* __restrict__ out)
{
    __shared__ float tile[32][33];
    const int t = threadIdx.x;
    const int j0 = blockIdx.x * 32, c0 = blockIdx.y * 32;
    {
        int jl = t >> 3, cl = (t & 7) * 4;
        float4 v = *(const float4*)(in + (size_t)(j0 + jl) * 1024 + c0 + cl);
        tile[jl][cl] = v.x; tile[jl][cl + 1] = v.y;
        tile[jl][cl + 2] = v.z; tile[jl][cl + 3] = v.w;
    }
    __syncthreads();
    {
        int cl = t >> 3, jl = (t & 7) * 4;
        bf16x4v o = { (bf16_t)tile[jl][cl], (bf16_t)tile[jl + 1][cl],
                      (bf16_t)tile[jl + 2][cl], (bf16_t)tile[jl + 3][cl] };
        *(bf16x4v*)&out[(size_t)(c0 + cl) * 2048 + j0 + jl] = o;
    }
}

// ---------------------------------------------------------------------------
// Fused GAT softmax-aggregate via MFMA.  Grid (32, 8) x 256.
// ---------------------------------------------------------------------------
__global__ __launch_bounds__(256)
void gat_agg_mfma(const bf16_t* __restrict__ hgT, const float* __restrict__ e1t,
                  const float* __restrict__ e2t, const float* __restrict__ feat,
                  float* __restrict__ outp)
{
    const int it = blockIdx.x, h = blockIdx.y;
    const int i0 = it * 64;
    __shared__ float e2s[2048];
    __shared__ float e1s[64], mS[64], lSinv[64];
    __shared__ float pm[256], pl[256];
    __shared__ __align__(16) bf16_t Ps[64 * 136];
    __shared__ __align__(16) bf16_t Hs[128 * 136];
    const int t = threadIdx.x;
    const int lane = t & 63, wave = t >> 6;
    const int q = lane >> 4, lr = lane & 15;
    const int wm = wave * 32;

    for (int idx = t; idx < 2048; idx += 256) e2s[idx] = e2t[h * 2048 + idx];
    if (t < 64) e1s[t] = e1t[h * 2048 + i0 + t];
    __syncthreads();

    {   // pass 1: online max/denominator per row i (4 j-groups)
        int il = t & 63, jt = t >> 6;
        float ev = e1s[il];
        float m = -1e30f, l = 0.f;
        for (int j = jt; j < 2048; j += 4) {
            float x = ev + e2s[j];
            x = (x >= 0.f) ? x : 0.2f * x;
            if (x > m) { l = l * __expf(m - x) + 1.0f; m = x; }
            else       { l += __expf(x - m); }
        }
        pm[t] = m; pl[t] = l;
        __syncthreads();
        if (t < 64) {
            float M = pm[t], L = pl[t];
            #pragma unroll
            for (int g2 = 1; g2 < 4; g2++) {
                float m2 = pm[g2 * 64 + t], l2 = pl[g2 * 64 + t];
                if (m2 > M) { L = L * __expf(M - m2) + l2; M = m2; }
                else        { L += l2 * __expf(m2 - M); }
            }
            mS[t] = M; lSinv[t] = 1.0f / L;
        }
        __syncthreads();
    }

    f32x4 acc[4][2];
    #pragma unroll
    for (int a = 0; a < 4; a++)
        #pragma unroll
        for (int b = 0; b < 2; b++) acc[a][b] = (f32x4){0.f, 0.f, 0.f, 0.f};

    for (int j0 = 0; j0 < 2048; j0 += 128) {
        for (int idx = t; idx < 2048; idx += 256) {
            int d = idx >> 4, seg = idx & 15;
            *(bf16x8*)&Hs[d * 136 + seg * 8] =
                *(const bf16x8*)&hgT[(size_t)(h * 128 + d) * 2048 + j0 + seg * 8];
        }
        for (int idx = t; idx < 1024; idx += 256) {
            int i = idx >> 4, jg = idx & 15;
            float ei = e1s[i], mi = mS[i];
            bf16x8 pv;
            #pragma unroll
            for (int u = 0; u < 8; u++) {
                float x = ei + e2s[j0 + jg * 8 + u];
                x = (x >= 0.f) ? x : 0.2f * x;
                pv[u] = (bf16_t)__expf(x - mi);
            }
            *(bf16x8*)&Ps[i * 136 + jg * 8] = pv;
        }
        __syncthreads();
        #pragma unroll
        for (int kb = 0; kb < 4; kb++) {
            bf16x8 af[4], bf2[2];
            #pragma unroll
            for (int fn = 0; fn < 4; fn++)
                af[fn] = *(bf16x8*)&Ps[(fn * 16 + lr) * 136 + kb * 32 + q * 8];
            #pragma unroll
            for (int fm = 0; fm < 2; fm++)
                bf2[fm] = *(bf16x8*)&Hs[(wm + fm * 16 + lr) * 136 + kb * 32 + q * 8];
            #pragma unroll
            for (int fn = 0; fn < 4; fn++)
                #pragma unroll
                for (int fm = 0; fm < 2; fm++)
                    acc[fn][fm] = __builtin_amdgcn_mfma_f32_16x16x32_bf16(
                        af[fn], bf2[fm], acc[fn][fm], 0, 0, 0);
        }
        __syncthreads();
    }

    #pragma unroll
    for (int fn = 0; fn < 4; fn++) {
        #pragma unroll
        for (int r = 0; r < 4; r++) {
            int il = fn * 16 + q * 4 + r;
            int i = i0 + il;
            float inv = lSinv[il];
            #pragma unroll
            for (int fm = 0; fm < 2; fm++) {
                int col = h * 128 + wm + fm * 16 + lr;
                float v = acc[fn][fm][r] * inv;
                v = (v > 0.f) ? v : (expf(v) - 1.0f);
                size_t off = (size_t)i * 1024 + col;
                outp[off] = v + feat[off];
            }
        }
    }
}

// ---------------------------------------------------------------------------
extern "C" void kernel_launch(void* const* d_in, const int* in_sizes, int n_in,
                              void* d_out, int out_size, void* d_ws, size_t ws_size,
                              hipStream_t stream)
{
    const float* feat = (const float*)d_in[0];
    const float *cw[5], *cb[5];
    if (in_sizes[2] == 1024) {
        for (int i = 0; i < 5; i++) { cw[i] = (const float*)d_in[1 + 2*i]; cb[i] = (const float*)d_in[2 + 2*i]; }
    } else {
        for (int i = 0; i < 5; i++) { cw[i] = (const float*)d_in[1 + i];   cb[i] = (const float*)d_in[6 + i]; }
    }
    const float* fp_w = (const float*)d_in[11];
    const float* fp_b = (const float*)d_in[12];
    const float* ln_g = (const float*)d_in[13];
    const float* ln_b = (const float*)d_in[14];
    const float* wq = (const float*)d_in[15]; const float* bq = (const float*)d_in[16];
    const float* wk = (const float*)d_in[17]; const float* bk = (const float*)d_in[18];
    const float* wv = (const float*)d_in[19]; const float* bv = (const float*)d_in[20];
    const float* wo = (const float*)d_in[21]; const float* bo = (const float*)d_in[22];
    const float* gat_w = (const float*)d_in[23]; const float* gat_b = (const float*)d_in[24];
    const float* ga1 = (const float*)d_in[25]; const float* ga2 = (const float*)d_in[26];
    float* outp = (float*)d_out;

    // ---- workspace layout (~118 MiB) ----
    char* wsb = (char*)d_ws;
    bf16_t* xb    = (bf16_t*)(wsb);                     //  4,194,304
    bf16_t* msb   = (bf16_t*)(wsb + 4194304);           // 20,971,520
    bf16_t* wcb   = (bf16_t*)(wsb + 25165824);          // 73,400,320
    float*  zf    = (float*) (wsb + 98566144);          //  8,388,608
    bf16_t* zb    = (bf16_t*)(wsb + 106954752);         //  4,194,304
    bf16_t* qb    = (bf16_t*)(wsb + 111149056);         //  4,194,304
    bf16_t* kb    = (bf16_t*)(wsb + 115343360);         //  4,194,304
    bf16_t* vb    = (bf16_t*)(wsb + 119537664);         //  4,194,304 (holds Vt [1024][2048])
    float*  cball = (float*) (wsb + 123731968);         //     20,480
    float*  e1t   = (float*) (wsb + 123752448);         //     65,536
    float*  e2t   = (float*) (wsb + 123817984);         //     65,536
    bf16_t* zpage = (bf16_t*)(wsb + 123883520);         //         64
    // aliases (stream-ordered reuse):
    bf16_t* fpwb = wcb;                 // wcb dead after conv GEMM
    bf16_t* wqb  = wcb + 5242880;
    bf16_t* wkb  = wqb + 1048576;
    bf16_t* wvb  = wkb + 1048576;
    bf16_t* wob  = wvb + 1048576;
    bf16_t* gwb  = wob + 1048576;
    bf16_t* ctxb = qb;                  // attn block writes exactly its own Q region
    bf16_t* attb = kb;                  // kb dead after attn
    float*  hgb  = zf;                  // zf dead after ln_gelu
    bf16_t* hgtb = msb;                 // msb dead after fusion GEMM

    const dim3 blk(256);

    // 1) conversions + conv weight reorder (+ zero page)
    cvt_f32_bf16<<<dim3(2048), blk, 0, stream>>>(feat, xb, 524288);
    reorder_convw<<<dim3(20480), blk, 0, stream>>>(cw[0], cw[1], cw[2], cw[3], cw[4], wcb);
    gather_bias<<<dim3(20), blk, 0, stream>>>(cb[0], cb[1], cb[2], cb[3], cb[4], cball, zpage);

    // 2) all 5 dilated convs, one MFMA launch -> msb (bf16, ld 5120)
    mfma_gemm<true, true><<<dim3(40, 16), blk, 0, stream>>>(
        xb, wcb, cball, msb, zpage, 1024, 1024, 1024, 5120, 0);

    // 3) remaining weight conversions
    cvt_f32_bf16<<<dim3(5120), blk, 0, stream>>>(fp_w, fpwb, 1310720);
    cvt_f32_bf16<<<dim3(1024), blk, 0, stream>>>(wq, wqb, 262144);
    cvt_f32_bf16<<<dim3(1024), blk, 0, stream>>>(wk, wkb, 262144);
    cvt_f32_bf16<<<dim3(1024), blk, 0, stream>>>(wv, wvb, 262144);
    cvt_f32_bf16<<<dim3(1024), blk, 0, stream>>>(wo, wob, 262144);
    cvt_f32_bf16<<<dim3(1024), blk, 0, stream>>>(gat_w, gwb, 262144);

    // 4) fusion projection -> zf (fp32)
    mfma_gemm<false, false><<<dim3(8, 16), blk, 0, stream>>>(
        msb, fpwb, fp_b, zf, zpage, 5120, 5120, 5120, 1024, 0);

    // 5) LN + GELU -> zf (fp32) and zb (bf16)
    ln_gelu<<<dim3(2048), blk, 0, stream>>>(zf, zb, ln_g, ln_b);

    // 6) Q,K projections (token-major) ; V projection operand-swapped ->
    //    Vt[dim][token] directly (A = Wv rows, B = z tokens, ldo = 2048).
    mfma_gemm<false, true><<<dim3(8, 16), blk, 0, stream>>>(zb, wqb, bq, qb, zpage, 1024, 1024, 1024, 1024, 0);
    mfma_gemm<false, true><<<dim3(8, 16), blk, 0, stream>>>(zb, wkb, bk, kb, zpage, 1024, 1024, 1024, 1024, 0);
    mfma_gemm<false, true, true><<<dim3(16, 8), blk, 0, stream>>>(wvb, zb, bv, vb, zpage, 1024, 1024, 1024, 2048, 0);

    // 7) MFMA flash attention -> ctxb (bf16)
    attn_mfma<<<dim3(2, 16, 8), blk, 0, stream>>>(qb, kb, vb, ctxb);

    // 8) output projection -> attb (bf16)
    mfma_gemm<false, true><<<dim3(8, 16), blk, 0, stream>>>(ctxb, wob, bo, attb, zpage, 1024, 1024, 1024, 1024, 0);

    // 9) GAT projection -> hgb (fp32)
    mfma_gemm<false, false><<<dim3(8, 16), blk, 0, stream>>>(attb, gwb, gat_b, hgb, zpage, 1024, 1024, 1024, 1024, 0);

    // 10) GAT: transpose hg, logits, fused softmax-aggregate (MFMA)
    transpose_hg<<<dim3(64, 32), blk, 0, stream>>>(hgb, hgtb);
    gat_e<<<dim3(64), blk, 0, stream>>>(hgb, ga1, ga2, e1t, e2t);
    gat_agg_mfma<<<dim3(32, 8), blk, 0, stream>>>(hgtb, e1t, e2t, feat, outp);
}

// Round 2
// 823.230 us; speedup vs baseline: 1.3213x; 1.0344x over previous
//
#include <hip/hip_runtime.h>
#include <hip/hip_bf16.h>

typedef __bf16 bf16_t;
typedef bf16_t bf16x8 __attribute__((ext_vector_type(8)));
typedef bf16_t bf16x4v __attribute__((ext_vector_type(4)));
typedef float f32x4 __attribute__((ext_vector_type(4)));

// async 16B global->LDS (direct, no VGPR round trip)
__device__ __forceinline__ void gll16(const bf16_t* g, bf16_t* l) {
    __builtin_amdgcn_global_load_lds(
        (const __attribute__((address_space(1))) unsigned int*)g,
        (__attribute__((address_space(3))) unsigned int*)l, 16, 0, 0);
}

// ---------------------------------------------------------------------------
// fp32 -> bf16 elementwise (n multiple of 4)
// ---------------------------------------------------------------------------
__global__ __launch_bounds__(256)
void cvt_f32_bf16(const float* __restrict__ in, bf16_t* __restrict__ out, int n4)
{
    int i = blockIdx.x * 256 + threadIdx.x;
    if (i < n4) {
        float4 v = ((const float4*)in)[i];
        bf16x4v o = { (bf16_t)v.x, (bf16_t)v.y, (bf16_t)v.z, (bf16_t)v.w };
        *(bf16x4v*)&out[i * 4] = o;
    }
}

// ---------------------------------------------------------------------------
// Reorder conv weights (O,C,7) fp32 -> bf16 planes [(i*7+kk)][o][c]
// ---------------------------------------------------------------------------
__global__ __launch_bounds__(256)
void reorder_convw(const float* w0, const float* w1, const float* w2,
                   const float* w3, const float* w4, bf16_t* __restrict__ out)
{
    int gid = blockIdx.x * 256 + threadIdx.x;       // < 5*1024*1024
    int i = gid >> 20, rem = gid & 1048575;
    int o = rem >> 10, c = rem & 1023;
    const float* ws[5] = {w0, w1, w2, w3, w4};
    const float* src = ws[i] + (size_t)o * 7168 + c * 7;
    #pragma unroll
    for (int kk = 0; kk < 7; kk++)
        out[((size_t)(i * 7 + kk) << 20) + (o << 10) + c] = (bf16_t)src[kk];
}

// conv biases -> cball[5120]; bq||bk -> qkbias[2048]; zero page init
__global__ __launch_bounds__(256)
void gather_bias(const float* b0, const float* b1, const float* b2,
                 const float* b3, const float* b4,
                 const float* bq, const float* bk,
                 float* __restrict__ out, float* __restrict__ qkbias,
                 bf16_t* __restrict__ zp)
{
    int idx = blockIdx.x * 256 + threadIdx.x;       // grid 28 -> 7168
    if (blockIdx.x == 0 && threadIdx.x < 32) zp[threadIdx.x] = (bf16_t)0.0f;
    if (idx < 5120) {
        const float* bs[5] = {b0, b1, b2, b3, b4};
        out[idx] = bs[idx >> 10][idx & 1023];
    } else {
        int j = idx - 5120;                          // < 2048
        qkbias[j] = (j < 1024) ? bq[j] : bk[j - 1024];
    }
}

// ---------------------------------------------------------------------------
// bf16 MFMA NT GEMM: out[n, m] = sum_k A[n,k]*B[m,k] + bias[...]
// Tile 128x128, BK=32, 4 waves (2x2 of 64x64), 16x16x32 MFMA.
//
// Depth-2 pipelined staging: 3 LDS buffers; stage(s+2) issued each iteration;
// raw s_barrier + counted "s_waitcnt vmcnt(4)" (vmcnt(0) only on last iter) so
// prefetch loads stay in flight across the barrier.  One barrier per K-step.
//
// LDS slot swizzle: 16B slot within a 32-elem row is XORed with (row>>1)&3 --
// applied on the *global source* column (global_load_lds dest stays linear)
// and on the ds_read slot.  Makes 8 consecutive lanes cover all 8 16B slots
// of a 128B bank row -> conflict-free ds_read_b128.
//
// BIAS_ROW: bias indexed by n (row) instead of oc0+m (for transposed-out GEMM).
// ---------------------------------------------------------------------------
template<bool CONV, bool OUT_BF16, bool BIAS_ROW = false>
__global__ __launch_bounds__(256)
void mfma_gemm(const bf16_t* __restrict__ A, const bf16_t* __restrict__ Bw,
               const float* __restrict__ bias, void* __restrict__ outv,
               const bf16_t* __restrict__ zp,
               int Kd, int lda, int ldb, int ldo, int out_col0)
{
    __shared__ __align__(16) bf16_t As[3][128 * 32];
    __shared__ __align__(16) bf16_t Bs[3][128 * 32];
    const int t = threadIdx.x;
    const int lane = t & 63, wave = t >> 6;
    const int wn = (wave & 1) * 64, wm = (wave >> 1) * 64;
    const int q = lane >> 4, lr = lane & 15;
    const int mt = CONV ? (blockIdx.x & 7) : blockIdx.x;
    const int conv_i = CONV ? (blockIdx.x >> 3) : 0;
    const int m0 = mt * 128, n0 = blockIdx.y * 128;
    const int srow = lane >> 2, sseg = lane & 3;           // staging row/16B-seg
    const int sw_seg = sseg ^ ((srow >> 1) & 3);           // swizzled source seg
    const int slotq = (q ^ ((lr >> 1) & 3)) * 8;           // swizzled read slot

    f32x4 acc[4][4];
    #pragma unroll
    for (int a = 0; a < 4; a++)
        #pragma unroll
        for (int b = 0; b < 4; b++) acc[a][b] = (f32x4){0.f, 0.f, 0.f, 0.f};

    const int ksteps = Kd >> 5;
    const int T = CONV ? ksteps * 7 : ksteps;

    // stage cursor (advanced once per stage call, in issue order)
    int s_tap = 0, s_k0 = 0;
    auto do_stage = [&](int bi) {
        const bf16_t* Bp = CONV ? (Bw + ((size_t)(conv_i * 7 + s_tap) << 20)) : Bw;
        const int shift = CONV ? ((s_tap - 3) << conv_i) : 0;
        bf16_t* Ab = &As[bi][0];
        bf16_t* Bb = &Bs[bi][0];
        #pragma unroll
        for (int p = 0; p < 2; p++) {
            const int slab = p * 64 + wave * 16;   // 16-row slab base
            const int rr = slab + srow;
            const bf16_t* ga;
            if (CONV) {
                int n = n0 + rr;
                int tg = (n & 255) + shift;
                ga = ((unsigned)tg < 256u)
                   ? A + (size_t)((n & ~255) + tg) * lda + s_k0 + sw_seg * 8
                   : zp + sseg * 8;
            } else {
                ga = A + (size_t)(n0 + rr) * lda + s_k0 + sw_seg * 8;
            }
            gll16(ga, &Ab[slab * 32]);
            gll16(Bp + (size_t)(m0 + rr) * ldb + s_k0 + sw_seg * 8, &Bb[slab * 32]);
        }
        s_k0 += 32;
        if (CONV && s_k0 == Kd) { s_k0 = 0; s_tap++; }
    };

    // prologue: 2 tiles in flight (8 outstanding loads/wave)
    do_stage(0);
    do_stage(1);

    int cur = 0;
    for (int s = 0; s < T; s++) {
        if (s + 1 < T) asm volatile("s_waitcnt vmcnt(4)" ::: "memory");
        else           asm volatile("s_waitcnt vmcnt(0)" ::: "memory");
        __builtin_amdgcn_s_barrier();
        __builtin_amdgcn_sched_barrier(0);
        int nb = cur + 2; if (nb >= 3) nb -= 3;
        if (s + 2 < T) do_stage(nb);

        bf16x8 af[4], bfv[4];
        #pragma unroll
        for (int f = 0; f < 4; f++) {
            af[f]  = *(bf16x8*)&As[cur][(wn + f * 16 + lr) * 32 + slotq];
            bfv[f] = *(bf16x8*)&Bs[cur][(wm + f * 16 + lr) * 32 + slotq];
        }
        __builtin_amdgcn_s_setprio(1);
        #pragma unroll
        for (int fn = 0; fn < 4; fn++)
            #pragma unroll
            for (int fm = 0; fm < 4; fm++)
                acc[fn][fm] = __builtin_amdgcn_mfma_f32_16x16x32_bf16(
                    af[fn], bfv[fm], acc[fn][fm], 0, 0, 0);
        __builtin_amdgcn_s_setprio(0);
        cur++; if (cur == 3) cur = 0;
    }

    const int oc0 = CONV ? (conv_i << 10) : out_col0;
    #pragma unroll
    for (int fn = 0; fn < 4; fn++) {
        #pragma unroll
        for (int r = 0; r < 4; r++) {
            int n = n0 + wn + fn * 16 + q * 4 + r;
            #pragma unroll
            for (int fm = 0; fm < 4; fm++) {
                int m = m0 + wm + fm * 16 + lr;
                float v = acc[fn][fm][r];
                if (bias) v += bias[BIAS_ROW ? n : (oc0 + m)];
                if (OUT_BF16)
                    ((bf16_t*)outv)[(size_t)n * ldo + oc0 + m] = (bf16_t)v;
                else
                    ((float*)outv)[(size_t)n * ldo + oc0 + m] = v;
            }
        }
    }
}

// ---------------------------------------------------------------------------
// LayerNorm (eps 1e-5) + exact GELU, in place on z (fp32) + bf16 copy zb.
// ---------------------------------------------------------------------------
__global__ __launch_bounds__(256)
void ln_gelu(float* __restrict__ z, bf16_t* __restrict__ zb,
             const float* __restrict__ g, const float* __restrict__ b)
{
    __shared__ float r1[256], r2[256];
    const int n = blockIdx.x, t = threadIdx.x;
    float* row = z + (size_t)n * 1024;
    float x[4], s = 0.f, s2 = 0.f;
    #pragma unroll
    for (int u = 0; u < 4; u++) {
        x[u] = row[t + u * 256];
        s += x[u]; s2 += x[u] * x[u];
    }
    r1[t] = s; r2[t] = s2;
    __syncthreads();
    for (int off = 128; off > 0; off >>= 1) {
        if (t < off) { r1[t] += r1[t + off]; r2[t] += r2[t + off]; }
        __syncthreads();
    }
    const float mu  = r1[0] * (1.0f / 1024.0f);
    const float var = r2[0] * (1.0f / 1024.0f) - mu * mu;
    const float rstd = rsqrtf(var + 1e-5f);
    #pragma unroll
    for (int u = 0; u < 4; u++) {
        int c = t + u * 256;
        float y = (x[u] - mu) * rstd * g[c] + b[c];
        float gv = 0.5f * y * (1.0f + erff(y * 0.70710678118654752f));
        row[c] = gv;
        zb[(size_t)n * 1024 + c] = (bf16_t)gv;
    }
}

// ---------------------------------------------------------------------------
// MFMA flash attention.
// Grid (2 i-tiles x 16 heads x 8 batch) = 256 blocks, 4 waves.
// q,k: interleaved QK buffer [2048][2048] bf16 (cols 0-1023 = Q, 1024-2047 = K);
// qg/kg point at the respective column halves, row stride 2048.
// vt: [1024 dims][2048 tokens] bf16 (operand-swapped V projection GEMM).
// ctx: [2048][1024].  LDS XOR-swizzled (16B slot ^= row&7).
// ---------------------------------------------------------------------------
__global__ __launch_bounds__(256)
void attn_mfma(const bf16_t* __restrict__ qg, const bf16_t* __restrict__ kg,
               const bf16_t* __restrict__ vt, bf16_t* __restrict__ ctx)
{
    const int it = blockIdx.x, h = blockIdx.y, bb = blockIdx.z;
    const int t = threadIdx.x, lane = t & 63, wave = t >> 6;
    const int q4 = lane >> 4, lr = lane & 15;
    const size_t qkbase = (size_t)bb * 256 * 2048 + (size_t)h * 64;

    __shared__ __align__(16) bf16_t Qs[4][32 * 64];   // per-wave Q rows
    __shared__ __align__(16) bf16_t Ks[64 * 64];      // K chunk  [j][d]
    __shared__ __align__(16) bf16_t Vs[64 * 64];      // Vt chunk [d][j]
    __shared__ __align__(16) bf16_t Ps[4][32 * 64];   // per-wave P tile [i][j]

    // ---- stage Q (128 rows x 64, swizzled), cooperative ----
    {
        const int itbase = it * 128;
        #pragma unroll
        for (int rep = 0; rep < 4; rep++) {
            int idx = rep * 256 + t;
            int rl = idx >> 3, seg = idx & 7;
            bf16x8 v = *(const bf16x8*)&qg[qkbase + (size_t)(itbase + rl) * 2048 + seg * 8];
            *(bf16x8*)&Qs[rl >> 5][(rl & 31) * 64 + ((seg ^ (rl & 7)) << 3)] = v;
        }
    }

    f32x4 o[2][4];                 // O accum: [fn rows][fd d-frag]
    float mrow[2][4], lrow[2][4];  // online softmax state per (fn, r)
    #pragma unroll
    for (int fn = 0; fn < 2; fn++)
        #pragma unroll
        for (int x = 0; x < 4; x++) {
            o[fn][x] = (f32x4){0.f, 0.f, 0.f, 0.f};
            mrow[fn][x] = -1e30f; lrow[fn][x] = 0.f;
        }

    for (int j0 = 0; j0 < 256; j0 += 64) {
        __syncthreads();           // prev chunk's K/V reads done (also covers Q stage)
        // ---- stage K chunk [64 j][64 d] and Vt chunk [64 d][64 j], swizzled ----
        #pragma unroll
        for (int rep = 0; rep < 2; rep++) {
            int idx = rep * 256 + t;
            int rl = idx >> 3, seg = idx & 7;
            bf16x8 kv = *(const bf16x8*)&kg[qkbase + (size_t)(j0 + rl) * 2048 + seg * 8];
            *(bf16x8*)&Ks[rl * 64 + ((seg ^ (rl & 7)) << 3)] = kv;
            bf16x8 vv = *(const bf16x8*)&vt[(size_t)(h * 64 + rl) * 2048 + bb * 256 + j0 + seg * 8];
            *(bf16x8*)&Vs[rl * 64 + ((seg ^ (rl & 7)) << 3)] = vv;
        }
        __syncthreads();

        // ---- S = Q K^T  (wave's 32 rows x 64 j) ----
        f32x4 s[2][4];
        #pragma unroll
        for (int fn = 0; fn < 2; fn++)
            #pragma unroll
            for (int fm = 0; fm < 4; fm++) s[fn][fm] = (f32x4){0.f, 0.f, 0.f, 0.f};
        #pragma unroll
        for (int kk = 0; kk < 2; kk++) {
            bf16x8 aq[2], bk[4];
            #pragma unroll
            for (int fn = 0; fn < 2; fn++) {
                int row = fn * 16 + lr;
                aq[fn] = *(bf16x8*)&Qs[wave][row * 64 + (((kk * 4 + q4) ^ (row & 7)) << 3)];
            }
            #pragma unroll
            for (int fm = 0; fm < 4; fm++) {
                int row = fm * 16 + lr;
                bk[fm] = *(bf16x8*)&Ks[row * 64 + (((kk * 4 + q4) ^ (row & 7)) << 3)];
            }
            #pragma unroll
            for (int fn = 0; fn < 2; fn++)
                #pragma unroll
                for (int fm = 0; fm < 4; fm++)
                    s[fn][fm] = __builtin_amdgcn_mfma_f32_16x16x32_bf16(
                        aq[fn], bk[fm], s[fn][fm], 0, 0, 0);
        }

        // ---- online softmax update + P (bf16) into wave-private LDS ----
        #pragma unroll
        for (int fn = 0; fn < 2; fn++) {
            #pragma unroll
            for (int r = 0; r < 4; r++) {
                float sv[4];
                #pragma unroll
                for (int fm = 0; fm < 4; fm++) sv[fm] = s[fn][fm][r] * 0.125f;
                float rm = fmaxf(fmaxf(sv[0], sv[1]), fmaxf(sv[2], sv[3]));
                rm = fmaxf(rm, __shfl_xor(rm, 1));
                rm = fmaxf(rm, __shfl_xor(rm, 2));
                rm = fmaxf(rm, __shfl_xor(rm, 4));
                rm = fmaxf(rm, __shfl_xor(rm, 8));
                float mold = mrow[fn][r];
                float mnew = fmaxf(mold, rm);
                float scl = __expf(mold - mnew);
                mrow[fn][r] = mnew;
                int prow = fn * 16 + q4 * 4 + r;
                float psum = 0.f;
                #pragma unroll
                for (int fm = 0; fm < 4; fm++) {
                    float p = __expf(sv[fm] - mnew);
                    psum += p;
                    int col = fm * 16 + lr;
                    Ps[wave][prow * 64 + (col ^ ((prow & 7) << 3))] = (bf16_t)p;
                }
                psum += __shfl_xor(psum, 1);
                psum += __shfl_xor(psum, 2);
                psum += __shfl_xor(psum, 4);
                psum += __shfl_xor(psum, 8);
                lrow[fn][r] = lrow[fn][r] * scl + psum;
                #pragma unroll
                for (int fd = 0; fd < 4; fd++) o[fn][fd][r] *= scl;
            }
        }

        // ---- O += P V  (wave-private Ps: in-order same-wave DS, no barrier) ----
        #pragma unroll
        for (int kk = 0; kk < 2; kk++) {
            bf16x8 ap[2], bvf[4];
            #pragma unroll
            for (int fn = 0; fn < 2; fn++) {
                int row = fn * 16 + lr;
                ap[fn] = *(bf16x8*)&Ps[wave][row * 64 + (((kk * 4 + q4) ^ (row & 7)) << 3)];
            }
            #pragma unroll
            for (int fd = 0; fd < 4; fd++) {
                int row = fd * 16 + lr;
                bvf[fd] = *(bf16x8*)&Vs[row * 64 + (((kk * 4 + q4) ^ (row & 7)) << 3)];
            }
            #pragma unroll
            for (int fn = 0; fn < 2; fn++)
                #pragma unroll
                for (int fd = 0; fd < 4; fd++)
                    o[fn][fd] = __builtin_amdgcn_mfma_f32_16x16x32_bf16(
                        ap[fn], bvf[fd], o[fn][fd], 0, 0, 0);
        }
    }

    // ---- epilogue: normalize, write ctx ----
    const int i0 = it * 128 + wave * 32;
    #pragma unroll
    for (int fn = 0; fn < 2; fn++) {
        #pragma unroll
        for (int r = 0; r < 4; r++) {
            float inv = 1.0f / lrow[fn][r];
            int row = i0 + fn * 16 + q4 * 4 + r;
            #pragma unroll
            for (int fd = 0; fd < 4; fd++) {
                int col = h * 64 + fd * 16 + lr;
                ctx[(size_t)bb * 262144 + (size_t)row * 1024 + col] =
                    (bf16_t)(o[fn][fd][r] * inv);
            }
        }
    }
}

// ---------------------------------------------------------------------------
// GAT logits, TRANSPOSED out: e1t[h][n] = hg[n,h,:].a1 ; e2t likewise.
// ---------------------------------------------------------------------------
__global__ __launch_bounds__(256)
void gat_e(const float* __restrict__ hg, const float* __restrict__ a1,
           const float* __restrict__ a2, float* __restrict__ e1t,
           float* __restrict__ e2t)
{
    int id = blockIdx.x * 256 + threadIdx.x;  // < 16384
    int h = id >> 11, n = id & 2047;
    const float* hr = hg + (size_t)n * 1024 + h * 128;
    float s1 = 0.f, s2 = 0.f;
    for (int d = 0; d < 128; d++) {
        float x = hr[d];
        s1 += x * a1[d];
        s2 += x * a2[d];
    }
    e1t[id] = s1; e2t[id] = s2;
}

// ---------------------------------------------------------------------------
// Transpose hg (2048 x 1024, fp32) -> hgT (1024 x 2048, bf16), 32x32 tiles.
// ---------------------------------------------------------------------------
__global__ __launch_bounds__(256)
void transpose_hg(const float* __restrict__ in, bf16_t* __restrict__ out)
{
    __shared__ float tile[32][33];
    const int t = threadIdx.x;
    const int j0 = blockIdx.x * 32, c0 = blockIdx.y * 32;
    {
        int jl = t >> 3, cl = (t & 7) * 4;
        float4 v = *(const float4*)(in + (size_t)(j0 + jl) * 1024 + c0 + cl);
        tile[jl][cl] = v.x; tile[jl][cl + 1] = v.y;
        tile[jl][cl + 2] = v.z; tile[jl][cl + 3] = v.w;
    }
    __syncthreads();
    {
        int cl = t >> 3, jl = (t & 7) * 4;
        bf16x4v o = { (bf16_t)tile[jl][cl], (bf16_t)tile[jl + 1][cl],
                      (bf16_t)tile[jl + 2][cl], (bf16_t)tile[jl + 3][cl] };
        *(bf16x4v*)&out[(size_t)(c0 + cl) * 2048 + j0 + jl] = o;
    }
}

// ---------------------------------------------------------------------------
// Fused GAT softmax-aggregate via MFMA.  Grid (32, 8) x 256.
// ---------------------------------------------------------------------------
__global__ __launch_bounds__(256)
void gat_agg_mfma(const bf16_t* __restrict__ hgT, const float* __restrict__ e1t,
                  const float* __restrict__ e2t, const float* __restrict__ feat,
                  float* __restrict__ outp)
{
    const int it = blockIdx.x, h = blockIdx.y;
    const int i0 = it * 64;
    __shared__ float e2s[2048];
    __shared__ float e1s[64], mS[64], lSinv[64];
    __shared__ float pm[256], pl[256];
    __shared__ __align__(16) bf16_t Ps[64 * 136];
    __shared__ __align__(16) bf16_t Hs[128 * 136];
    const int t = threadIdx.x;
    const int lane = t & 63, wave = t >> 6;
    const int q = lane >> 4, lr = lane & 15;
    const int wm = wave * 32;

    for (int idx = t; idx < 2048; idx += 256) e2s[idx] = e2t[h * 2048 + idx];
    if (t < 64) e1s[t] = e1t[h * 2048 + i0 + t];
    __syncthreads();

    {   // pass 1: online max/denominator per row i (4 j-groups)
        int il = t & 63, jt = t >> 6;
        float ev = e1s[il];
        float m = -1e30f, l = 0.f;
        for (int j = jt; j < 2048; j += 4) {
            float x = ev + e2s[j];
            x = (x >= 0.f) ? x : 0.2f * x;
            if (x > m) { l = l * __expf(m - x) + 1.0f; m = x; }
            else       { l += __expf(x - m); }
        }
        pm[t] = m; pl[t] = l;
        __syncthreads();
        if (t < 64) {
            float M = pm[t], L = pl[t];
            #pragma unroll
            for (int g2 = 1; g2 < 4; g2++) {
                float m2 = pm[g2 * 64 + t], l2 = pl[g2 * 64 + t];
                if (m2 > M) { L = L * __expf(M - m2) + l2; M = m2; }
                else        { L += l2 * __expf(m2 - M); }
            }
            mS[t] = M; lSinv[t] = 1.0f / L;
        }
        __syncthreads();
    }

    f32x4 acc[4][2];
    #pragma unroll
    for (int a = 0; a < 4; a++)
        #pragma unroll
        for (int b = 0; b < 2; b++) acc[a][b] = (f32x4){0.f, 0.f, 0.f, 0.f};

    for (int j0 = 0; j0 < 2048; j0 += 128) {
        for (int idx = t; idx < 2048; idx += 256) {
            int d = idx >> 4, seg = idx & 15;
            *(bf16x8*)&Hs[d * 136 + seg * 8] =
                *(const bf16x8*)&hgT[(size_t)(h * 128 + d) * 2048 + j0 + seg * 8];
        }
        for (int idx = t; idx < 1024; idx += 256) {
            int i = idx >> 4, jg = idx & 15;
            float ei = e1s[i], mi = mS[i];
            bf16x8 pv;
            #pragma unroll
            for (int u = 0; u < 8; u++) {
                float x = ei + e2s[j0 + jg * 8 + u];
                x = (x >= 0.f) ? x : 0.2f * x;
                pv[u] = (bf16_t)__expf(x - mi);
            }
            *(bf16x8*)&Ps[i * 136 + jg * 8] = pv;
        }
        __syncthreads();
        #pragma unroll
        for (int kb = 0; kb < 4; kb++) {
            bf16x8 af[4], bf2[2];
            #pragma unroll
            for (int fn = 0; fn < 4; fn++)
                af[fn] = *(bf16x8*)&Ps[(fn * 16 + lr) * 136 + kb * 32 + q * 8];
            #pragma unroll
            for (int fm = 0; fm < 2; fm++)
                bf2[fm] = *(bf16x8*)&Hs[(wm + fm * 16 + lr) * 136 + kb * 32 + q * 8];
            #pragma unroll
            for (int fn = 0; fn < 4; fn++)
                #pragma unroll
                for (int fm = 0; fm < 2; fm++)
                    acc[fn][fm] = __builtin_amdgcn_mfma_f32_16x16x32_bf16(
                        af[fn], bf2[fm], acc[fn][fm], 0, 0, 0);
        }
        __syncthreads();
    }

    #pragma unroll
    for (int fn = 0; fn < 4; fn++) {
        #pragma unroll
        for (int r = 0; r < 4; r++) {
            int il = fn * 16 + q * 4 + r;
            int i = i0 + il;
            float inv = lSinv[il];
            #pragma unroll
            for (int fm = 0; fm < 2; fm++) {
                int col = h * 128 + wm + fm * 16 + lr;
                float v = acc[fn][fm][r] * inv;
                v = (v > 0.f) ? v : (expf(v) - 1.0f);
                size_t off = (size_t)i * 1024 + col;
                outp[off] = v + feat[off];
            }
        }
    }
}

// ---------------------------------------------------------------------------
extern "C" void kernel_launch(void* const* d_in, const int* in_sizes, int n_in,
                              void* d_out, int out_size, void* d_ws, size_t ws_size,
                              hipStream_t stream)
{
    const float* feat = (const float*)d_in[0];
    const float *cw[5], *cb[5];
    if (in_sizes[2] == 1024) {
        for (int i = 0; i < 5; i++) { cw[i] = (const float*)d_in[1 + 2*i]; cb[i] = (const float*)d_in[2 + 2*i]; }
    } else {
        for (int i = 0; i < 5; i++) { cw[i] = (const float*)d_in[1 + i];   cb[i] = (const float*)d_in[6 + i]; }
    }
    const float* fp_w = (const float*)d_in[11];
    const float* fp_b = (const float*)d_in[12];
    const float* ln_g = (const float*)d_in[13];
    const float* ln_b = (const float*)d_in[14];
    const float* wq = (const float*)d_in[15]; const float* bq = (const float*)d_in[16];
    const float* wk = (const float*)d_in[17]; const float* bk = (const float*)d_in[18];
    const float* wv = (const float*)d_in[19]; const float* bv = (const float*)d_in[20];
    const float* wo = (const float*)d_in[21]; const float* bo = (const float*)d_in[22];
    const float* gat_w = (const float*)d_in[23]; const float* gat_b = (const float*)d_in[24];
    const float* ga1 = (const float*)d_in[25]; const float* ga2 = (const float*)d_in[26];
    float* outp = (float*)d_out;

    // ---- workspace layout (~118 MiB) ----
    char* wsb = (char*)d_ws;
    bf16_t* xb    = (bf16_t*)(wsb);                     //  4,194,304
    bf16_t* msb   = (bf16_t*)(wsb + 4194304);           // 20,971,520
    bf16_t* wcb   = (bf16_t*)(wsb + 25165824);          // 73,400,320
    float*  zf    = (float*) (wsb + 98566144);          //  8,388,608
    bf16_t* zb    = (bf16_t*)(wsb + 106954752);         //  4,194,304
    bf16_t* qb    = (bf16_t*)(wsb + 111149056);         //  4,194,304
    bf16_t* kb    = (bf16_t*)(wsb + 115343360);         //  4,194,304
    bf16_t* vb    = (bf16_t*)(wsb + 119537664);         //  4,194,304 (Vt [1024][2048])
    float*  cball = (float*) (wsb + 123731968);         //     20,480
    float*  e1t   = (float*) (wsb + 123752448);         //     65,536
    float*  e2t   = (float*) (wsb + 123817984);         //     65,536
    bf16_t* zpage = (bf16_t*)(wsb + 123883520);         //         64
    // aliases (stream-ordered reuse):
    bf16_t* fpwb = wcb;                 // wcb dead after conv GEMM
    bf16_t* wqb  = wcb + 5242880;       // wq||wk contiguous for merged QK GEMM
    bf16_t* wkb  = wqb + 1048576;
    bf16_t* wvb  = wkb + 1048576;
    bf16_t* wob  = wvb + 1048576;
    bf16_t* gwb  = wob + 1048576;
    bf16_t* qkb  = qb;                  // merged QK output [2048][2048] (qb+kb)
    float*  qkbias = e1t;               // e1t not needed until step 10
    bf16_t* ctxb = zb;                  // zb dead after QK/V projections
    bf16_t* attb = kb;                  // qkb dead after attn
    float*  hgb  = zf;                  // zf dead after ln_gelu
    bf16_t* hgtb = msb;                 // msb dead after fusion GEMM

    const dim3 blk(256);

    // 1) conversions + conv weight reorder (+ bias gathers, zero page)
    cvt_f32_bf16<<<dim3(2048), blk, 0, stream>>>(feat, xb, 524288);
    reorder_convw<<<dim3(20480), blk, 0, stream>>>(cw[0], cw[1], cw[2], cw[3], cw[4], wcb);
    gather_bias<<<dim3(28), blk, 0, stream>>>(cb[0], cb[1], cb[2], cb[3], cb[4],
                                              bq, bk, cball, qkbias, zpage);

    // 2) all 5 dilated convs, one MFMA launch -> msb (bf16, ld 5120)
    mfma_gemm<true, true><<<dim3(40, 16), blk, 0, stream>>>(
        xb, wcb, cball, msb, zpage, 1024, 1024, 1024, 5120, 0);

    // 3) remaining weight conversions
    cvt_f32_bf16<<<dim3(5120), blk, 0, stream>>>(fp_w, fpwb, 1310720);
    cvt_f32_bf16<<<dim3(1024), blk, 0, stream>>>(wq, wqb, 262144);
    cvt_f32_bf16<<<dim3(1024), blk, 0, stream>>>(wk, wkb, 262144);
    cvt_f32_bf16<<<dim3(1024), blk, 0, stream>>>(wv, wvb, 262144);
    cvt_f32_bf16<<<dim3(1024), blk, 0, stream>>>(wo, wob, 262144);
    cvt_f32_bf16<<<dim3(1024), blk, 0, stream>>>(gat_w, gwb, 262144);

    // 4) fusion projection -> zf (fp32)
    mfma_gemm<false, false><<<dim3(8, 16), blk, 0, stream>>>(
        msb, fpwb, fp_b, zf, zpage, 5120, 5120, 5120, 1024, 0);

    // 5) LN + GELU -> zf (fp32) and zb (bf16)
    ln_gelu<<<dim3(2048), blk, 0, stream>>>(zf, zb, ln_g, ln_b);

    // 6) merged Q+K projection -> qkb [2048][2048]; V operand-swapped -> Vt
    mfma_gemm<false, true><<<dim3(16, 16), blk, 0, stream>>>(
        zb, wqb, qkbias, qkb, zpage, 1024, 1024, 1024, 2048, 0);
    mfma_gemm<false, true, true><<<dim3(16, 8), blk, 0, stream>>>(
        wvb, zb, bv, vb, zpage, 1024, 1024, 1024, 2048, 0);

    // 7) MFMA flash attention -> ctxb (bf16)
    attn_mfma<<<dim3(2, 16, 8), blk, 0, stream>>>(qkb, qkb + 1024, vb, ctxb);

    // 8) output projection -> attb (bf16)
    mfma_gemm<false, true><<<dim3(8, 16), blk, 0, stream>>>(ctxb, wob, bo, attb, zpage, 1024, 1024, 1024, 1024, 0);

    // 9) GAT projection -> hgb (fp32)
    mfma_gemm<false, false><<<dim3(8, 16), blk, 0, stream>>>(attb, gwb, gat_b, hgb, zpage, 1024, 1024, 1024, 1024, 0);

    // 10) GAT: transpose hg, logits, fused softmax-aggregate (MFMA)
    transpose_hg<<<dim3(64, 32), blk, 0, stream>>>(hgb, hgtb);
    gat_e<<<dim3(64), blk, 0, stream>>>(hgb, ga1, ga2, e1t, e2t);
    gat_agg_mfma<<<dim3(32, 8), blk, 0, stream>>>(hgtb, e1t, e2t, feat, outp);
}

// Round 3
// 709.635 us; speedup vs baseline: 1.5328x; 1.1601x over previous
//
#include <hip/hip_runtime.h>
#include <hip/hip_bf16.h>

typedef __bf16 bf16_t;
typedef bf16_t bf16x8 __attribute__((ext_vector_type(8)));
typedef bf16_t bf16x4v __attribute__((ext_vector_type(4)));
typedef float f32x4 __attribute__((ext_vector_type(4)));

// async 16B global->LDS (direct, no VGPR round trip)
__device__ __forceinline__ void gll16(const bf16_t* g, bf16_t* l) {
    __builtin_amdgcn_global_load_lds(
        (const __attribute__((address_space(1))) unsigned int*)g,
        (__attribute__((address_space(3))) unsigned int*)l, 16, 0, 0);
}

// ---------------------------------------------------------------------------
// fp32 -> bf16 elementwise (n multiple of 4)
// ---------------------------------------------------------------------------
__global__ __launch_bounds__(256)
void cvt_f32_bf16(const float* __restrict__ in, bf16_t* __restrict__ out, int n4)
{
    int i = blockIdx.x * 256 + threadIdx.x;
    if (i < n4) {
        float4 v = ((const float4*)in)[i];
        bf16x4v o = { (bf16_t)v.x, (bf16_t)v.y, (bf16_t)v.z, (bf16_t)v.w };
        *(bf16x4v*)&out[i * 4] = o;
    }
}

// ---------------------------------------------------------------------------
// Merged fp32->bf16 for 6 weight tensors (fp_w + wq/wk/wv/wo/gat_w), 1 launch.
// ---------------------------------------------------------------------------
__global__ __launch_bounds__(256)
void cvt_multi(const float* __restrict__ fpw, const float* __restrict__ wq,
               const float* __restrict__ wk, const float* __restrict__ wv,
               const float* __restrict__ wo, const float* __restrict__ gw,
               bf16_t* __restrict__ fpwb, bf16_t* __restrict__ wqb,
               bf16_t* __restrict__ wkb, bf16_t* __restrict__ wvb,
               bf16_t* __restrict__ wob, bf16_t* __restrict__ gwb)
{
    int id = blockIdx.x * 256 + threadIdx.x;    // < 2621440
    const float* src; bf16_t* dst; int off;
    if (id < 1310720) { src = fpw; dst = fpwb; off = id; }
    else {
        int id3 = id - 1310720;
        int w = id3 >> 18; off = id3 & 262143;
        const float* ss[5] = {wq, wk, wv, wo, gw};
        bf16_t* dd[5] = {wqb, wkb, wvb, wob, gwb};
        src = ss[w]; dst = dd[w];
    }
    float4 v = ((const float4*)src)[off];
    bf16x4v o = { (bf16_t)v.x, (bf16_t)v.y, (bf16_t)v.z, (bf16_t)v.w };
    *(bf16x4v*)&dst[off * 4] = o;
}

// ---------------------------------------------------------------------------
// Reorder conv weights (O,C,7) fp32 -> bf16 planes [(i*7+kk)][o][c]
// ---------------------------------------------------------------------------
__global__ __launch_bounds__(256)
void reorder_convw(const float* w0, const float* w1, const float* w2,
                   const float* w3, const float* w4, bf16_t* __restrict__ out)
{
    int gid = blockIdx.x * 256 + threadIdx.x;       // < 5*1024*1024
    int i = gid >> 20, rem = gid & 1048575;
    int o = rem >> 10, c = rem & 1023;
    const float* ws[5] = {w0, w1, w2, w3, w4};
    const float* src = ws[i] + (size_t)o * 7168 + c * 7;
    #pragma unroll
    for (int kk = 0; kk < 7; kk++)
        out[((size_t)(i * 7 + kk) << 20) + (o << 10) + c] = (bf16_t)src[kk];
}

// conv biases -> cball[5120]; bq||bk -> qkbias[2048]; zero page init
__global__ __launch_bounds__(256)
void gather_bias(const float* b0, const float* b1, const float* b2,
                 const float* b3, const float* b4,
                 const float* bq, const float* bk,
                 float* __restrict__ out, float* __restrict__ qkbias,
                 bf16_t* __restrict__ zp)
{
    int idx = blockIdx.x * 256 + threadIdx.x;       // grid 28 -> 7168
    if (blockIdx.x == 0 && threadIdx.x < 32) zp[threadIdx.x] = (bf16_t)0.0f;
    if (idx < 5120) {
        const float* bs[5] = {b0, b1, b2, b3, b4};
        out[idx] = bs[idx >> 10][idx & 1023];
    } else {
        int j = idx - 5120;                          // < 2048
        qkbias[j] = (j < 1024) ? bq[j] : bk[j - 1024];
    }
}

// ---------------------------------------------------------------------------
// bf16 MFMA NT GEMM: out[n, m] = sum_k A[n,k]*B[m,k] + bias[...]
// Tile NRx128 (NR in {128,64}), BK=32, 4 waves, 16x16x32 MFMA.
//
// Depth-2 pipelined staging, 3 LDS buffers, counted vmcnt (never 0 in steady
// state).  Per K-step phase order: wait(tile s) -> barrier -> sched_barrier
// -> ds_read fragments(tile s) -> issue stage(tile s+2) -> MFMA.  The stage
// issue + address VALU overlaps the lgkm wait and MFMA cluster.
//
// LDS slot swizzle: 16B slot ^= (row>>1)&3, applied on the *global source*
// column (linear global_load_lds dest) and on the ds_read slot -> 8
// consecutive lanes hit all 8 slots of a 128B bank row (conflict-free).
//
// BIAS_ROW: bias indexed by n (row) instead of oc0+m (transposed-out GEMM).
// ---------------------------------------------------------------------------
template<bool CONV, bool OUT_BF16, bool BIAS_ROW = false, int NR = 128>
__global__ __launch_bounds__(256)
void mfma_gemm(const bf16_t* __restrict__ A, const bf16_t* __restrict__ Bw,
               const float* __restrict__ bias, void* __restrict__ outv,
               const bf16_t* __restrict__ zp,
               int Kd, int lda, int ldb, int ldo, int out_col0)
{
    constexpr int FN = NR / 32;                  // 4 (NR=128) or 2 (NR=64)
    __shared__ __align__(16) bf16_t As[3][NR * 32];
    __shared__ __align__(16) bf16_t Bs[3][128 * 32];
    const int t = threadIdx.x;
    const int lane = t & 63, wave = t >> 6;
    const int wn = (wave & 1) * (NR / 2), wm = (wave >> 1) * 64;
    const int q = lane >> 4, lr = lane & 15;
    const int mt = CONV ? (blockIdx.x & 7) : blockIdx.x;
    const int conv_i = CONV ? (blockIdx.x >> 3) : 0;
    const int m0 = mt * 128, n0 = blockIdx.y * NR;
    const int srow = lane >> 2, sseg = lane & 3;           // staging row/16B-seg
    const int sw_seg = sseg ^ ((srow >> 1) & 3);           // swizzled source seg
    const int slotq = (q ^ ((lr >> 1) & 3)) * 8;           // swizzled read slot

    f32x4 acc[FN][4];
    #pragma unroll
    for (int a = 0; a < FN; a++)
        #pragma unroll
        for (int b = 0; b < 4; b++) acc[a][b] = (f32x4){0.f, 0.f, 0.f, 0.f};

    const int ksteps = Kd >> 5;
    const int T = CONV ? ksteps * 7 : ksteps;

    // stage cursor (advanced once per stage call, in issue order)
    int s_tap = 0, s_k0 = 0;
    auto do_stage = [&](int bi) {
        const bf16_t* Bp = CONV ? (Bw + ((size_t)(conv_i * 7 + s_tap) << 20)) : Bw;
        const int shift = CONV ? ((s_tap - 3) << conv_i) : 0;
        #pragma unroll
        for (int p = 0; p < NR / 64; p++) {
            const int slab = p * 64 + wave * 16;   // 16-row slab base
            const int rr = slab + srow;
            const bf16_t* ga;
            if (CONV) {
                int n = n0 + rr;
                int tg = (n & 255) + shift;
                ga = ((unsigned)tg < 256u)
                   ? A + (size_t)((n & ~255) + tg) * lda + s_k0 + sw_seg * 8
                   : zp + sseg * 8;
            } else {
                ga = A + (size_t)(n0 + rr) * lda + s_k0 + sw_seg * 8;
            }
            gll16(ga, &As[bi][slab * 32]);
        }
        #pragma unroll
        for (int p = 0; p < 2; p++) {
            const int slab = p * 64 + wave * 16;
            const int rr = slab + srow;
            gll16(Bp + (size_t)(m0 + rr) * ldb + s_k0 + sw_seg * 8, &Bs[bi][slab * 32]);
        }
        s_k0 += 32;
        if (CONV && s_k0 == Kd) { s_k0 = 0; s_tap++; }
    };

    // prologue: 2 tiles in flight
    do_stage(0);
    do_stage(1);

    int cur = 0;
    for (int s = 0; s < T; s++) {
        if (s + 1 < T) {
            if constexpr (NR == 128) asm volatile("s_waitcnt vmcnt(4)" ::: "memory");
            else                     asm volatile("s_waitcnt vmcnt(3)" ::: "memory");
        } else {
            asm volatile("s_waitcnt vmcnt(0)" ::: "memory");
        }
        __builtin_amdgcn_s_barrier();
        __builtin_amdgcn_sched_barrier(0);

        // fragments first -- lgkm wait overlaps the stage issue below
        bf16x8 af[FN], bfv[4];
        #pragma unroll
        for (int f = 0; f < FN; f++)
            af[f] = *(bf16x8*)&As[cur][(wn + f * 16 + lr) * 32 + slotq];
        #pragma unroll
        for (int f = 0; f < 4; f++)
            bfv[f] = *(bf16x8*)&Bs[cur][(wm + f * 16 + lr) * 32 + slotq];

        int nb = cur + 2; if (nb >= 3) nb -= 3;
        if (s + 2 < T) do_stage(nb);

        __builtin_amdgcn_s_setprio(1);
        #pragma unroll
        for (int fn = 0; fn < FN; fn++)
            #pragma unroll
            for (int fm = 0; fm < 4; fm++)
                acc[fn][fm] = __builtin_amdgcn_mfma_f32_16x16x32_bf16(
                    af[fn], bfv[fm], acc[fn][fm], 0, 0, 0);
        __builtin_amdgcn_s_setprio(0);
        cur++; if (cur == 3) cur = 0;
    }

    const int oc0 = CONV ? (conv_i << 10) : out_col0;
    #pragma unroll
    for (int fn = 0; fn < FN; fn++) {
        #pragma unroll
        for (int r = 0; r < 4; r++) {
            int n = n0 + wn + fn * 16 + q * 4 + r;
            #pragma unroll
            for (int fm = 0; fm < 4; fm++) {
                int m = m0 + wm + fm * 16 + lr;
                float v = acc[fn][fm][r];
                if (bias) v += bias[BIAS_ROW ? n : (oc0 + m)];
                if (OUT_BF16)
                    ((bf16_t*)outv)[(size_t)n * ldo + oc0 + m] = (bf16_t)v;
                else
                    ((float*)outv)[(size_t)n * ldo + oc0 + m] = v;
            }
        }
    }
}

// ---------------------------------------------------------------------------
// LayerNorm (eps 1e-5) + exact GELU, in place on z (fp32) + bf16 copy zb.
// ---------------------------------------------------------------------------
__global__ __launch_bounds__(256)
void ln_gelu(float* __restrict__ z, bf16_t* __restrict__ zb,
             const float* __restrict__ g, const float* __restrict__ b)
{
    __shared__ float r1[256], r2[256];
    const int n = blockIdx.x, t = threadIdx.x;
    float* row = z + (size_t)n * 1024;
    float x[4], s = 0.f, s2 = 0.f;
    #pragma unroll
    for (int u = 0; u < 4; u++) {
        x[u] = row[t + u * 256];
        s += x[u]; s2 += x[u] * x[u];
    }
    r1[t] = s; r2[t] = s2;
    __syncthreads();
    for (int off = 128; off > 0; off >>= 1) {
        if (t < off) { r1[t] += r1[t + off]; r2[t] += r2[t + off]; }
        __syncthreads();
    }
    const float mu  = r1[0] * (1.0f / 1024.0f);
    const float var = r2[0] * (1.0f / 1024.0f) - mu * mu;
    const float rstd = rsqrtf(var + 1e-5f);
    #pragma unroll
    for (int u = 0; u < 4; u++) {
        int c = t + u * 256;
        float y = (x[u] - mu) * rstd * g[c] + b[c];
        float gv = 0.5f * y * (1.0f + erff(y * 0.70710678118654752f));
        row[c] = gv;
        zb[(size_t)n * 1024 + c] = (bf16_t)gv;
    }
}

// ---------------------------------------------------------------------------
// MFMA flash attention.
// Grid (2 i-tiles x 16 heads x 8 batch) = 256 blocks, 4 waves.
// q,k: interleaved QK buffer [2048][2048] bf16 (cols 0-1023 = Q, 1024-2047 = K);
// vt: [1024 dims][2048 tokens] bf16.  ctx: [2048][1024].
// LDS XOR-swizzled (16B slot ^= row&7).
// ---------------------------------------------------------------------------
__global__ __launch_bounds__(256)
void attn_mfma(const bf16_t* __restrict__ qg, const bf16_t* __restrict__ kg,
               const bf16_t* __restrict__ vt, bf16_t* __restrict__ ctx)
{
    const int it = blockIdx.x, h = blockIdx.y, bb = blockIdx.z;
    const int t = threadIdx.x, lane = t & 63, wave = t >> 6;
    const int q4 = lane >> 4, lr = lane & 15;
    const size_t qkbase = (size_t)bb * 256 * 2048 + (size_t)h * 64;

    __shared__ __align__(16) bf16_t Qs[4][32 * 64];   // per-wave Q rows
    __shared__ __align__(16) bf16_t Ks[64 * 64];      // K chunk  [j][d]
    __shared__ __align__(16) bf16_t Vs[64 * 64];      // Vt chunk [d][j]
    __shared__ __align__(16) bf16_t Ps[4][32 * 64];   // per-wave P tile [i][j]

    // ---- stage Q (128 rows x 64, swizzled), cooperative ----
    {
        const int itbase = it * 128;
        #pragma unroll
        for (int rep = 0; rep < 4; rep++) {
            int idx = rep * 256 + t;
            int rl = idx >> 3, seg = idx & 7;
            bf16x8 v = *(const bf16x8*)&qg[qkbase + (size_t)(itbase + rl) * 2048 + seg * 8];
            *(bf16x8*)&Qs[rl >> 5][(rl & 31) * 64 + ((seg ^ (rl & 7)) << 3)] = v;
        }
    }

    f32x4 o[2][4];                 // O accum: [fn rows][fd d-frag]
    float mrow[2][4], lrow[2][4];  // online softmax state per (fn, r)
    #pragma unroll
    for (int fn = 0; fn < 2; fn++)
        #pragma unroll
        for (int x = 0; x < 4; x++) {
            o[fn][x] = (f32x4){0.f, 0.f, 0.f, 0.f};
            mrow[fn][x] = -1e30f; lrow[fn][x] = 0.f;
        }

    for (int j0 = 0; j0 < 256; j0 += 64) {
        __syncthreads();           // prev chunk's K/V reads done (also covers Q stage)
        // ---- stage K chunk [64 j][64 d] and Vt chunk [64 d][64 j], swizzled ----
        #pragma unroll
        for (int rep = 0; rep < 2; rep++) {
            int idx = rep * 256 + t;
            int rl = idx >> 3, seg = idx & 7;
            bf16x8 kv = *(const bf16x8*)&kg[qkbase + (size_t)(j0 + rl) * 2048 + seg * 8];
            *(bf16x8*)&Ks[rl * 64 + ((seg ^ (rl & 7)) << 3)] = kv;
            bf16x8 vv = *(const bf16x8*)&vt[(size_t)(h * 64 + rl) * 2048 + bb * 256 + j0 + seg * 8];
            *(bf16x8*)&Vs[rl * 64 + ((seg ^ (rl & 7)) << 3)] = vv;
        }
        __syncthreads();

        // ---- S = Q K^T  (wave's 32 rows x 64 j) ----
        f32x4 s[2][4];
        #pragma unroll
        for (int fn = 0; fn < 2; fn++)
            #pragma unroll
            for (int fm = 0; fm < 4; fm++) s[fn][fm] = (f32x4){0.f, 0.f, 0.f, 0.f};
        #pragma unroll
        for (int kk = 0; kk < 2; kk++) {
            bf16x8 aq[2], bk[4];
            #pragma unroll
            for (int fn = 0; fn < 2; fn++) {
                int row = fn * 16 + lr;
                aq[fn] = *(bf16x8*)&Qs[wave][row * 64 + (((kk * 4 + q4) ^ (row & 7)) << 3)];
            }
            #pragma unroll
            for (int fm = 0; fm < 4; fm++) {
                int row = fm * 16 + lr;
                bk[fm] = *(bf16x8*)&Ks[row * 64 + (((kk * 4 + q4) ^ (row & 7)) << 3)];
            }
            #pragma unroll
            for (int fn = 0; fn < 2; fn++)
                #pragma unroll
                for (int fm = 0; fm < 4; fm++)
                    s[fn][fm] = __builtin_amdgcn_mfma_f32_16x16x32_bf16(
                        aq[fn], bk[fm], s[fn][fm], 0, 0, 0);
        }

        // ---- online softmax update + P (bf16) into wave-private LDS ----
        #pragma unroll
        for (int fn = 0; fn < 2; fn++) {
            #pragma unroll
            for (int r = 0; r < 4; r++) {
                float sv[4];
                #pragma unroll
                for (int fm = 0; fm < 4; fm++) sv[fm] = s[fn][fm][r] * 0.125f;
                float rm = fmaxf(fmaxf(sv[0], sv[1]), fmaxf(sv[2], sv[3]));
                rm = fmaxf(rm, __shfl_xor(rm, 1));
                rm = fmaxf(rm, __shfl_xor(rm, 2));
                rm = fmaxf(rm, __shfl_xor(rm, 4));
                rm = fmaxf(rm, __shfl_xor(rm, 8));
                float mold = mrow[fn][r];
                float mnew = fmaxf(mold, rm);
                float scl = __expf(mold - mnew);
                mrow[fn][r] = mnew;
                int prow = fn * 16 + q4 * 4 + r;
                float psum = 0.f;
                #pragma unroll
                for (int fm = 0; fm < 4; fm++) {
                    float p = __expf(sv[fm] - mnew);
                    psum += p;
                    int col = fm * 16 + lr;
                    Ps[wave][prow * 64 + (col ^ ((prow & 7) << 3))] = (bf16_t)p;
                }
                psum += __shfl_xor(psum, 1);
                psum += __shfl_xor(psum, 2);
                psum += __shfl_xor(psum, 4);
                psum += __shfl_xor(psum, 8);
                lrow[fn][r] = lrow[fn][r] * scl + psum;
                #pragma unroll
                for (int fd = 0; fd < 4; fd++) o[fn][fd][r] *= scl;
            }
        }

        // ---- O += P V  (wave-private Ps: in-order same-wave DS, no barrier) ----
        #pragma unroll
        for (int kk = 0; kk < 2; kk++) {
            bf16x8 ap[2], bvf[4];
            #pragma unroll
            for (int fn = 0; fn < 2; fn++) {
                int row = fn * 16 + lr;
                ap[fn] = *(bf16x8*)&Ps[wave][row * 64 + (((kk * 4 + q4) ^ (row & 7)) << 3)];
            }
            #pragma unroll
            for (int fd = 0; fd < 4; fd++) {
                int row = fd * 16 + lr;
                bvf[fd] = *(bf16x8*)&Vs[row * 64 + (((kk * 4 + q4) ^ (row & 7)) << 3)];
            }
            #pragma unroll
            for (int fn = 0; fn < 2; fn++)
                #pragma unroll
                for (int fd = 0; fd < 4; fd++)
                    o[fn][fd] = __builtin_amdgcn_mfma_f32_16x16x32_bf16(
                        ap[fn], bvf[fd], o[fn][fd], 0, 0, 0);
        }
    }

    // ---- epilogue: normalize, write ctx ----
    const int i0 = it * 128 + wave * 32;
    #pragma unroll
    for (int fn = 0; fn < 2; fn++) {
        #pragma unroll
        for (int r = 0; r < 4; r++) {
            float inv = 1.0f / lrow[fn][r];
            int row = i0 + fn * 16 + q4 * 4 + r;
            #pragma unroll
            for (int fd = 0; fd < 4; fd++) {
                int col = h * 64 + fd * 16 + lr;
                ctx[(size_t)bb * 262144 + (size_t)row * 1024 + col] =
                    (bf16_t)(o[fn][fd][r] * inv);
            }
        }
    }
}

// ---------------------------------------------------------------------------
// GAT logits, TRANSPOSED out: e1t[h][n] = hg[n,h,:].a1 ; e2t likewise.
// ---------------------------------------------------------------------------
__global__ __launch_bounds__(256)
void gat_e(const float* __restrict__ hg, const float* __restrict__ a1,
           const float* __restrict__ a2, float* __restrict__ e1t,
           float* __restrict__ e2t)
{
    int id = blockIdx.x * 256 + threadIdx.x;  // < 16384
    int h = id >> 11, n = id & 2047;
    const float* hr = hg + (size_t)n * 1024 + h * 128;
    float s1 = 0.f, s2 = 0.f;
    for (int d = 0; d < 128; d += 4) {
        float4 x = *(const float4*)&hr[d];
        float4 u1 = *(const float4*)&a1[d];
        float4 u2 = *(const float4*)&a2[d];
        s1 += x.x * u1.x + x.y * u1.y + x.z * u1.z + x.w * u1.w;
        s2 += x.x * u2.x + x.y * u2.y + x.z * u2.z + x.w * u2.w;
    }
    e1t[id] = s1; e2t[id] = s2;
}

// ---------------------------------------------------------------------------
// Transpose hg (2048 x 1024, fp32) -> hgT (1024 x 2048, bf16), 32x32 tiles.
// ---------------------------------------------------------------------------
__global__ __launch_bounds__(256)
void transpose_hg(const float* __restrict__ in, bf16_t* __restrict__ out)
{
    __shared__ float tile[32][33];
    const int t = threadIdx.x;
    const int j0 = blockIdx.x * 32, c0 = blockIdx.y * 32;
    {
        int jl = t >> 3, cl = (t & 7) * 4;
        float4 v = *(const float4*)(in + (size_t)(j0 + jl) * 1024 + c0 + cl);
        tile[jl][cl] = v.x; tile[jl][cl + 1] = v.y;
        tile[jl][cl + 2] = v.z; tile[jl][cl + 3] = v.w;
    }
    __syncthreads();
    {
        int cl = t >> 3, jl = (t & 7) * 4;
        bf16x4v o = { (bf16_t)tile[jl][cl], (bf16_t)tile[jl + 1][cl],
                      (bf16_t)tile[jl + 2][cl], (bf16_t)tile[jl + 3][cl] };
        *(bf16x4v*)&out[(size_t)(c0 + cl) * 2048 + j0 + jl] = o;
    }
}

// ---------------------------------------------------------------------------
// Fused GAT softmax-aggregate via MFMA.  Grid (32, 8) x 256.
// ---------------------------------------------------------------------------
__global__ __launch_bounds__(256)
void gat_agg_mfma(const bf16_t* __restrict__ hgT, const float* __restrict__ e1t,
                  const float* __restrict__ e2t, const float* __restrict__ feat,
                  float* __restrict__ outp)
{
    const int it = blockIdx.x, h = blockIdx.y;
    const int i0 = it * 64;
    __shared__ float e2s[2048];
    __shared__ float e1s[64], mS[64], lSinv[64];
    __shared__ float pm[256], pl[256];
    __shared__ __align__(16) bf16_t Ps[64 * 136];
    __shared__ __align__(16) bf16_t Hs[128 * 136];
    const int t = threadIdx.x;
    const int lane = t & 63, wave = t >> 6;
    const int q = lane >> 4, lr = lane & 15;
    const int wm = wave * 32;

    for (int idx = t; idx < 2048; idx += 256) e2s[idx] = e2t[h * 2048 + idx];
    if (t < 64) e1s[t] = e1t[h * 2048 + i0 + t];
    __syncthreads();

    {   // pass 1: online max/denominator per row i (4 j-groups)
        int il = t & 63, jt = t >> 6;
        float ev = e1s[il];
        float m = -1e30f, l = 0.f;
        for (int j = jt; j < 2048; j += 4) {
            float x = ev + e2s[j];
            x = (x >= 0.f) ? x : 0.2f * x;
            if (x > m) { l = l * __expf(m - x) + 1.0f; m = x; }
            else       { l += __expf(x - m); }
        }
        pm[t] = m; pl[t] = l;
        __syncthreads();
        if (t < 64) {
            float M = pm[t], L = pl[t];
            #pragma unroll
            for (int g2 = 1; g2 < 4; g2++) {
                float m2 = pm[g2 * 64 + t], l2 = pl[g2 * 64 + t];
                if (m2 > M) { L = L * __expf(M - m2) + l2; M = m2; }
                else        { L += l2 * __expf(m2 - M); }
            }
            mS[t] = M; lSinv[t] = 1.0f / L;
        }
        __syncthreads();
    }

    f32x4 acc[4][2];
    #pragma unroll
    for (int a = 0; a < 4; a++)
        #pragma unroll
        for (int b = 0; b < 2; b++) acc[a][b] = (f32x4){0.f, 0.f, 0.f, 0.f};

    for (int j0 = 0; j0 < 2048; j0 += 128) {
        for (int idx = t; idx < 2048; idx += 256) {
            int d = idx >> 4, seg = idx & 15;
            *(bf16x8*)&Hs[d * 136 + seg * 8] =
                *(const bf16x8*)&hgT[(size_t)(h * 128 + d) * 2048 + j0 + seg * 8];
        }
        for (int idx = t; idx < 1024; idx += 256) {
            int i = idx >> 4, jg = idx & 15;
            float ei = e1s[i], mi = mS[i];
            bf16x8 pv;
            #pragma unroll
            for (int u = 0; u < 8; u++) {
                float x = ei + e2s[j0 + jg * 8 + u];
                x = (x >= 0.f) ? x : 0.2f * x;
                pv[u] = (bf16_t)__expf(x - mi);
            }
            *(bf16x8*)&Ps[i * 136 + jg * 8] = pv;
        }
        __syncthreads();
        #pragma unroll
        for (int kb = 0; kb < 4; kb++) {
            bf16x8 af[4], bf2[2];
            #pragma unroll
            for (int fn = 0; fn < 4; fn++)
                af[fn] = *(bf16x8*)&Ps[(fn * 16 + lr) * 136 + kb * 32 + q * 8];
            #pragma unroll
            for (int fm = 0; fm < 2; fm++)
                bf2[fm] = *(bf16x8*)&Hs[(wm + fm * 16 + lr) * 136 + kb * 32 + q * 8];
            #pragma unroll
            for (int fn = 0; fn < 4; fn++)
                #pragma unroll
                for (int fm = 0; fm < 2; fm++)
                    acc[fn][fm] = __builtin_amdgcn_mfma_f32_16x16x32_bf16(
                        af[fn], bf2[fm], acc[fn][fm], 0, 0, 0);
        }
        __syncthreads();
    }

    #pragma unroll
    for (int fn = 0; fn < 4; fn++) {
        #pragma unroll
        for (int r = 0; r < 4; r++) {
            int il = fn * 16 + q * 4 + r;
            int i = i0 + il;
            float inv = lSinv[il];
            #pragma unroll
            for (int fm = 0; fm < 2; fm++) {
                int col = h * 128 + wm + fm * 16 + lr;
                float v = acc[fn][fm][r] * inv;
                v = (v > 0.f) ? v : (expf(v) - 1.0f);
                size_t off = (size_t)i * 1024 + col;
                outp[off] = v + feat[off];
            }
        }
    }
}

// ---------------------------------------------------------------------------
extern "C" void kernel_launch(void* const* d_in, const int* in_sizes, int n_in,
                              void* d_out, int out_size, void* d_ws, size_t ws_size,
                              hipStream_t stream)
{
    const float* feat = (const float*)d_in[0];
    const float *cw[5], *cb[5];
    if (in_sizes[2] == 1024) {
        for (int i = 0; i < 5; i++) { cw[i] = (const float*)d_in[1 + 2*i]; cb[i] = (const float*)d_in[2 + 2*i]; }
    } else {
        for (int i = 0; i < 5; i++) { cw[i] = (const float*)d_in[1 + i];   cb[i] = (const float*)d_in[6 + i]; }
    }
    const float* fp_w = (const float*)d_in[11];
    const float* fp_b = (const float*)d_in[12];
    const float* ln_g = (const float*)d_in[13];
    const float* ln_b = (const float*)d_in[14];
    const float* wq = (const float*)d_in[15]; const float* bq = (const float*)d_in[16];
    const float* wk = (const float*)d_in[17]; const float* bk = (const float*)d_in[18];
    const float* wv = (const float*)d_in[19]; const float* bv = (const float*)d_in[20];
    const float* wo = (const float*)d_in[21]; const float* bo = (const float*)d_in[22];
    const float* gat_w = (const float*)d_in[23]; const float* gat_b = (const float*)d_in[24];
    const float* ga1 = (const float*)d_in[25]; const float* ga2 = (const float*)d_in[26];
    float* outp = (float*)d_out;

    // ---- workspace layout (~118 MiB) ----
    char* wsb = (char*)d_ws;
    bf16_t* xb    = (bf16_t*)(wsb);                     //  4,194,304
    bf16_t* msb   = (bf16_t*)(wsb + 4194304);           // 20,971,520
    bf16_t* wcb   = (bf16_t*)(wsb + 25165824);          // 73,400,320
    float*  zf    = (float*) (wsb + 98566144);          //  8,388,608
    bf16_t* zb    = (bf16_t*)(wsb + 106954752);         //  4,194,304
    bf16_t* qb    = (bf16_t*)(wsb + 111149056);         //  4,194,304
    bf16_t* kb    = (bf16_t*)(wsb + 115343360);         //  4,194,304
    bf16_t* vb    = (bf16_t*)(wsb + 119537664);         //  4,194,304 (Vt [1024][2048])
    float*  cball = (float*) (wsb + 123731968);         //     20,480
    float*  e1t   = (float*) (wsb + 123752448);         //     65,536
    float*  e2t   = (float*) (wsb + 123817984);         //     65,536
    bf16_t* zpage = (bf16_t*)(wsb + 123883520);         //         64
    // aliases (stream-ordered reuse):
    bf16_t* fpwb = wcb;                 // wcb dead after conv GEMM
    bf16_t* wqb  = wcb + 5242880;       // wq||wk contiguous for merged QK GEMM
    bf16_t* wkb  = wqb + 1048576;
    bf16_t* wvb  = wkb + 1048576;
    bf16_t* wob  = wvb + 1048576;
    bf16_t* gwb  = wob + 1048576;
    bf16_t* qkb  = qb;                  // merged QK output [2048][2048] (qb+kb)
    float*  qkbias = e1t;               // e1t not needed until step 10
    bf16_t* ctxb = zb;                  // zb dead after QK/V projections
    bf16_t* attb = kb;                  // qkb dead after attn
    float*  hgb  = zf;                  // zf dead after ln_gelu
    bf16_t* hgtb = msb;                 // msb dead after fusion GEMM

    const dim3 blk(256);

    // 1) feat conversion + conv weight reorder + bias gathers + zero page
    cvt_f32_bf16<<<dim3(2048), blk, 0, stream>>>(feat, xb, 524288);
    reorder_convw<<<dim3(20480), blk, 0, stream>>>(cw[0], cw[1], cw[2], cw[3], cw[4], wcb);
    gather_bias<<<dim3(28), blk, 0, stream>>>(cb[0], cb[1], cb[2], cb[3], cb[4],
                                              bq, bk, cball, qkbias, zpage);

    // 2) all 5 dilated convs, one MFMA launch -> msb (bf16, ld 5120)
    mfma_gemm<true, true><<<dim3(40, 16), blk, 0, stream>>>(
        xb, wcb, cball, msb, zpage, 1024, 1024, 1024, 5120, 0);

    // 3) remaining weight conversions (single launch; aliases wcb, so after conv)
    cvt_multi<<<dim3(10240), blk, 0, stream>>>(fp_w, wq, wk, wv, wo, gat_w,
                                               fpwb, wqb, wkb, wvb, wob, gwb);

    // 4) fusion projection -> zf (fp32); 64-row tiles -> 256 blocks
    mfma_gemm<false, false, false, 64><<<dim3(8, 32), blk, 0, stream>>>(
        msb, fpwb, fp_b, zf, zpage, 5120, 5120, 5120, 1024, 0);

    // 5) LN + GELU -> zf (fp32) and zb (bf16)
    ln_gelu<<<dim3(2048), blk, 0, stream>>>(zf, zb, ln_g, ln_b);

    // 6) merged Q+K projection -> qkb [2048][2048]; V operand-swapped -> Vt
    mfma_gemm<false, true><<<dim3(16, 16), blk, 0, stream>>>(
        zb, wqb, qkbias, qkb, zpage, 1024, 1024, 1024, 2048, 0);
    mfma_gemm<false, true, true, 64><<<dim3(16, 16), blk, 0, stream>>>(
        wvb, zb, bv, vb, zpage, 1024, 1024, 1024, 2048, 0);

    // 7) MFMA flash attention -> ctxb (bf16)
    attn_mfma<<<dim3(2, 16, 8), blk, 0, stream>>>(qkb, qkb + 1024, vb, ctxb);

    // 8) output projection -> attb (bf16); 64-row tiles
    mfma_gemm<false, true, false, 64><<<dim3(8, 32), blk, 0, stream>>>(
        ctxb, wob, bo, attb, zpage, 1024, 1024, 1024, 1024, 0);

    // 9) GAT projection -> hgb (fp32); 64-row tiles
    mfma_gemm<false, false, false, 64><<<dim3(8, 32), blk, 0, stream>>>(
        attb, gwb, gat_b, hgb, zpage, 1024, 1024, 1024, 1024, 0);

    // 10) GAT: transpose hg, logits, fused softmax-aggregate (MFMA)
    transpose_hg<<<dim3(64, 32), blk, 0, stream>>>(hgb, hgtb);
    gat_e<<<dim3(64), blk, 0, stream>>>(hgb, ga1, ga2, e1t, e2t);
    gat_agg_mfma<<<dim3(32, 8), blk, 0, stream>>>(hgtb, e1t, e2t, feat, outp);
}